// Round 11
// baseline (99.819 us; speedup 1.0000x reference)
//
#include <hip/hip_runtime.h>

// Decoder: frames[m,c,k,l] = sum_n (mix[m,n,k]*mask[m,c,n,k]) * W[l,n]
// then overlap-add (hop=8) into out[m,c,t], T = (K-1)*8+16 = 128008.
// M=4 C=2 N=512 K=16000 L=16.
//
// TRAFFIC-MINIMAL + WIDE-LOAD + FULL-OCCUPANCY:
//  - both c's per thread: mix loaded once -> issued bytes = 393 MB minimum
//  - lane owns TWO consecutive k's: all streaming loads are float2
//    (512 B/wave-instr; r7 measured 10.2 B/cyc/CU at 16 waves/CU)
//  - 512-thread blocks (8 waves x 64 n's), BK=128, grid 500:
//    2 blocks/CU x 8 waves = 16 waves/CU at <=128 VGPR (launch_bounds 512,4)
// W via scalar path (uniform address -> s_load float4, constant cache).
// LDS: 63 KB reduce buffer (7 waves dump, wave 0 combines), two c-phases.
// Wave 0 overlap-adds in-register (odd frame in-lane, even via shfl_up);
// block-boundary head/tail partials -> d_ws; boundary_kernel combines:
// every out element written exactly once with '=' (no memset, no atomics).

#define M_   4
#define C_   2
#define N_   512
#define K_   16000
#define L_   16
#define HOP  8
#define T_   ((K_ - 1) * HOP + L_)   // 128008
#define BK   128                     // frames per block (2 per lane, 1 wave covers all)
#define NSEG 8                       // waves per block
#define NPW  (N_ / NSEG)             // 64 n's per wave
#define NCH  (NPW / 4)               // 16 chunks of 4 n's
#define NB   (K_ / BK)               // 125 k-blocks per m
#define GRID (M_ * NB)               // 500
#define RSTRIDE 36                   // reduce-buffer lane stride (floats)
#define WS_TAIL_OFF (M_ * C_ * NB * 8)

__global__ __launch_bounds__(512, 4)
void decoder_kernel(const float* __restrict__ mix,   // [M][N][K]
                    const float* __restrict__ mask,  // [M][C][N][K]
                    const float* __restrict__ Wg,    // [L][N]
                    float* __restrict__ out,         // [M][C][T]
                    float* __restrict__ ws) {
    __shared__ float lds[7 * 64 * RSTRIDE];          // 63 KB

    const int tid  = threadIdx.x;
    const int lane = tid & 63;
    const int w    = tid >> 6;                       // 0..7
    const int m    = blockIdx.x / NB;
    const int bb   = blockIdx.x % NB;
    const int k0   = bb * BK;

    float accE0[16], accO0[16], accE1[16], accO1[16];   // [c][parity][l]
    #pragma unroll
    for (int i = 0; i < 16; ++i) {
        accE0[i] = 0.f; accO0[i] = 0.f; accE1[i] = 0.f; accO1[i] = 0.f;
    }

    const int n0w  = w * NPW;
    const int n0wU = __builtin_amdgcn_readfirstlane(n0w);  // uniform -> s_load
    const int kk   = k0 + 2 * lane;                  // even frame of this lane

    const float* pm = mix  + (size_t)m * N_ * K_ + (size_t)n0w * K_ + kk;
    const float* p0 = mask + ((size_t)(m * C_) * N_ + n0w) * K_ + kk;
    const float* p1 = p0 + (size_t)N_ * K_;          // c=1 plane

    for (int ch = 0; ch < NCH; ++ch) {
        float2 mv[4], a0[4], a1[4];
        #pragma unroll
        for (int j = 0; j < 4; ++j) {
            mv[j] = *(const float2*)&pm[(size_t)j * K_];
            a0[j] = *(const float2*)&p0[(size_t)j * K_];
            a1[j] = *(const float2*)&p1[(size_t)j * K_];
        }
        float sE0[4], sO0[4], sE1[4], sO1[4];
        #pragma unroll
        for (int j = 0; j < 4; ++j) {
            sE0[j] = mv[j].x * a0[j].x;  sO0[j] = mv[j].y * a0[j].y;
            sE1[j] = mv[j].x * a1[j].x;  sO1[j] = mv[j].y * a1[j].y;
        }
        const int nbase = n0wU + ch * 4;             // scalar
        #pragma unroll
        for (int l = 0; l < L_; ++l) {
            const float4 w4 = *(const float4*)&Wg[l * N_ + nbase];  // s_load
            const float wv[4] = { w4.x, w4.y, w4.z, w4.w };
            #pragma unroll
            for (int j = 0; j < 4; ++j) {
                accE0[l] = fmaf(sE0[j], wv[j], accE0[l]);
                accO0[l] = fmaf(sO0[j], wv[j], accO0[l]);
                accE1[l] = fmaf(sE1[j], wv[j], accE1[l]);
                accO1[l] = fmaf(sO1[j], wv[j], accO1[l]);
            }
        }
        pm += (size_t)4 * K_;
        p0 += (size_t)4 * K_;
        p1 += (size_t)4 * K_;
    }

    // ---- cross-wave reduction through LDS, one phase per c ----
#define REDUCE_C(AE, AO)                                                      \
    {                                                                         \
        __syncthreads();                                                      \
        if (w > 0) {                                                          \
            float* rb = &lds[(w - 1) * (64 * RSTRIDE) + lane * RSTRIDE];      \
            _Pragma("unroll")                                                 \
            for (int i = 0; i < 4; ++i)                                       \
                *(float4*)&rb[i * 4] = make_float4(AE[i*4], AE[i*4+1],        \
                                                   AE[i*4+2], AE[i*4+3]);     \
            _Pragma("unroll")                                                 \
            for (int i = 0; i < 4; ++i)                                       \
                *(float4*)&rb[16 + i * 4] = make_float4(AO[i*4], AO[i*4+1],   \
                                                        AO[i*4+2], AO[i*4+3]);\
        }                                                                     \
        __syncthreads();                                                      \
        if (w == 0) {                                                         \
            _Pragma("unroll")                                                 \
            for (int r = 0; r < 7; ++r) {                                     \
                const float* rb = &lds[r * (64 * RSTRIDE) + lane * RSTRIDE];  \
                _Pragma("unroll")                                             \
                for (int i = 0; i < 4; ++i) {                                 \
                    const float4 v = *(const float4*)&rb[i * 4];              \
                    AE[i*4]   += v.x;  AE[i*4+1] += v.y;                      \
                    AE[i*4+2] += v.z;  AE[i*4+3] += v.w;                      \
                }                                                             \
                _Pragma("unroll")                                             \
                for (int i = 0; i < 4; ++i) {                                 \
                    const float4 v = *(const float4*)&rb[16 + i * 4];         \
                    AO[i*4]   += v.x;  AO[i*4+1] += v.y;                      \
                    AO[i*4+2] += v.z;  AO[i*4+3] += v.w;                      \
                }                                                             \
            }                                                                 \
        }                                                                     \
    }
    REDUCE_C(accE0, accO0)
    REDUCE_C(accE1, accO1)
#undef REDUCE_C

    // ---- overlap-add: t = k*8+j = frames[k][j] + frames[k-1][8+j] ----
    if (w == 0) {
#define EPILOGUE(AE, AO, CIDX)                                                \
        {                                                                     \
            float* ob = out + (size_t)(m * C_ + (CIDX)) * T_                  \
                            + (size_t)kk * HOP;                               \
            float cmbE[8], cmbO[8];                                           \
            _Pragma("unroll")                                                 \
            for (int j = 0; j < 8; ++j) {                                     \
                const float pv = __shfl_up(AO[8 + j], 1);                     \
                cmbE[j] = AE[j] + pv;            /* frames[kk-1][8+j] */      \
                cmbO[j] = AO[j] + AE[8 + j];     /* in-lane */                \
            }                                                                 \
            if (lane == 0) {                                                  \
                float* hb = ws + (size_t)((m * C_ + (CIDX)) * NB + bb) * 8;   \
                *(float4*)&hb[0] = make_float4(AE[0], AE[1], AE[2], AE[3]);   \
                *(float4*)&hb[4] = make_float4(AE[4], AE[5], AE[6], AE[7]);   \
            } else {                                                          \
                *(float4*)&ob[0] = make_float4(cmbE[0], cmbE[1],              \
                                               cmbE[2], cmbE[3]);             \
                *(float4*)&ob[4] = make_float4(cmbE[4], cmbE[5],              \
                                               cmbE[6], cmbE[7]);             \
            }                                                                 \
            *(float4*)&ob[8]  = make_float4(cmbO[0], cmbO[1],                 \
                                            cmbO[2], cmbO[3]);                \
            *(float4*)&ob[12] = make_float4(cmbO[4], cmbO[5],                 \
                                            cmbO[6], cmbO[7]);                \
            if (lane == 63) {                                                 \
                float* tb = ws + WS_TAIL_OFF                                  \
                             + (size_t)((m * C_ + (CIDX)) * NB + bb) * 8;     \
                *(float4*)&tb[0] = make_float4(AO[8],  AO[9],                 \
                                               AO[10], AO[11]);               \
                *(float4*)&tb[4] = make_float4(AO[12], AO[13],                \
                                               AO[14], AO[15]);               \
            }                                                                 \
        }
        EPILOGUE(accE0, accO0, 0)
        EPILOGUE(accE1, accO1, 1)
#undef EPILOGUE
    }
}

// out[bb*1024 + j] = head[bb] + tail[bb-1]; global tail = tail[NB-1].
__global__ __launch_bounds__(256)
void boundary_kernel(const float* __restrict__ ws, float* __restrict__ out) {
    const int id = blockIdx.x * 256 + threadIdx.x;
    const int total = M_ * C_ * NB * 8;
    if (id >= total) return;
    const int j  = id & 7;
    const int bb = (id >> 3) % NB;
    const int mc = (id >> 3) / NB;
    float v = ws[(size_t)(mc * NB + bb) * 8 + j];
    if (bb > 0) v += ws[WS_TAIL_OFF + (size_t)(mc * NB + bb - 1) * 8 + j];
    out[(size_t)mc * T_ + (size_t)bb * (BK * HOP) + j] = v;
    if (bb == NB - 1) {
        out[(size_t)mc * T_ + (size_t)K_ * HOP + j] =
            ws[WS_TAIL_OFF + (size_t)(mc * NB + bb) * 8 + j];
    }
}

extern "C" void kernel_launch(void* const* d_in, const int* in_sizes, int n_in,
                              void* d_out, int out_size, void* d_ws, size_t ws_size,
                              hipStream_t stream) {
    const float* mix  = (const float*)d_in[0];
    const float* mask = (const float*)d_in[1];
    const float* Wg   = (const float*)d_in[2];
    float* out = (float*)d_out;
    float* ws  = (float*)d_ws;

    decoder_kernel<<<dim3(GRID), dim3(512), 0, stream>>>(mix, mask, Wg, out, ws);
    boundary_kernel<<<dim3((M_ * C_ * NB * 8 + 255) / 256), dim3(256), 0, stream>>>(ws, out);
}

// Round 12
// 81.111 us; speedup vs baseline: 1.2307x; 1.2307x over previous
//
#include <hip/hip_runtime.h>

// Decoder: frames[m,c,k,l] = sum_n (mix[m,n,k]*mask[m,c,n,k]) * W[l,n]
// then overlap-add (hop=8) into out[m,c,t], T = (K-1)*8+16 = 128008.
// M=4 C=2 N=512 K=16000 L=16.
//
// LDS-SHARED-MIX variant (r11's register-held both-c spilled; this keeps
// r8's proven 64-VGPR per-wave budget while still reading mix ONCE):
//  - block = 512 threads = 8 waves = (g in 0..3 n-segments) x (c in 0..1);
//    each wave accumulates acc[16] for ONE c over 128 n's (its g-segment).
//  - per step (8 n's): the c=0 wave of pair g stages mix rows 0..3, the
//    c=1 wave stages rows 4..7 (regs -> LDS, 8 KB buffer); barrier; both
//    waves read all 8 rows from LDS (stride-1, conflict-free) and stream
//    their own mask plane from global. Vector-memory path bytes drop to
//    the 393 MB mandatory minimum (mix once + mask once); the mix re-read
//    rides the otherwise-idle DS pipe.
//  - 1 k per lane (BK=64), dword streaming loads, grid 1000, 4 blocks/CU
//    x 8 waves = 32 waves/CU at <=64 VGPR (launch_bounds(512,8)) -- the
//    exact configuration that measured 10.5 B/cyc/CU in r8.
// W via scalar path (uniform address -> s_load float4, constant cache).
// Reduction: per c, waves g=1..3 dump to LDS (reused stage memory, 30.7 KB
// total), wave g=0 of each c combines and runs the overlap-add epilogue in
// parallel. Block-boundary head/tail partials -> d_ws; boundary_kernel
// combines them: every out element written exactly once with '='.

#define M_   4
#define C_   2
#define N_   512
#define K_   16000
#define L_   16
#define HOP  8
#define T_   ((K_ - 1) * HOP + L_)   // 128008
#define BK   64                      // frames per block (1 per lane)
#define NB   (K_ / BK)               // 250 k-blocks per m
#define GRID (M_ * NB)               // 1000
#define NPW  128                     // n's per wave-pair (g-segment)
#define SG   8                       // n's staged per step
#define NSTEP (NPW / SG)             // 16
#define RSTRIDE 20                   // reduce-buffer lane stride (floats)
#define WS_TAIL_OFF (M_ * C_ * NB * 8)

__global__ __launch_bounds__(512, 8)
void decoder_kernel(const float* __restrict__ mix,   // [M][N][K]
                    const float* __restrict__ mask,  // [M][C][N][K]
                    const float* __restrict__ Wg,    // [L][N]
                    float* __restrict__ out,         // [M][C][T]
                    float* __restrict__ ws) {
    // stage region: first 4*8*64 = 2048 floats; reduce reuses all 7680.
    __shared__ float lds[7680];                      // 30.7 KB

    const int tid  = threadIdx.x;
    const int lane = tid & 63;
    const int w    = tid >> 6;       // 0..7
    const int c    = w >> 2;         // 0..1
    const int g    = w & 3;          // 0..3 (n-segment)
    const int m    = blockIdx.x / NB;
    const int bb   = blockIdx.x % NB;
    const int k0   = bb * BK;
    const int kk   = k0 + lane;

    float acc[16];
    #pragma unroll
    for (int i = 0; i < 16; ++i) acc[i] = 0.f;

    const int n0w  = g * NPW;
    const int n0wU = __builtin_amdgcn_readfirstlane(n0w);  // uniform -> s_load

    const float* pmix = mix  + (size_t)m * N_ * K_ + (size_t)n0w * K_ + kk;
    const float* pmsk = mask + ((size_t)(m * C_ + c) * N_ + n0w) * K_ + kk;

    float* stg = &lds[(g * SG) * 64];     // row r of this g at stg[r*64+lane]

    #pragma unroll 1
    for (int st = 0; st < NSTEP; ++st) {
        // ---- issue global loads early (mix first so its vmcnt drains first)
        float mr[4];                      // this wave's staged mix rows
        #pragma unroll
        for (int i = 0; i < 4; ++i)
            mr[i] = pmix[(size_t)(st * SG + c * 4 + i) * K_];
        float a[8];                       // mask rows (all 8, own c-plane)
        #pragma unroll
        for (int j = 0; j < 8; ++j)
            a[j] = pmsk[(size_t)(st * SG + j) * K_];

        __syncthreads();                  // prior step's stage reads complete
        #pragma unroll
        for (int i = 0; i < 4; ++i)
            stg[(c * 4 + i) * 64 + lane] = mr[i];
        __syncthreads();                  // stage visible to both c-waves

        // ---- compute 2 chunks of 4 n ----
        #pragma unroll
        for (int chh = 0; chh < 2; ++chh) {
            float s[4];
            #pragma unroll
            for (int j = 0; j < 4; ++j) {
                const float mv = stg[(chh * 4 + j) * 64 + lane];  // DS pipe
                s[j] = mv * a[chh * 4 + j];
            }
            const int nbase = n0wU + st * SG + chh * 4;           // scalar
            #pragma unroll
            for (int l = 0; l < L_; ++l) {
                const float4 w4 = *(const float4*)&Wg[l * N_ + nbase]; // s_load
                acc[l] = fmaf(s[0], w4.x, acc[l]);
                acc[l] = fmaf(s[1], w4.y, acc[l]);
                acc[l] = fmaf(s[2], w4.z, acc[l]);
                acc[l] = fmaf(s[3], w4.w, acc[l]);
            }
        }
    }

    // ---- reduction across g within each c (stage memory reused) ----
    __syncthreads();
    if (g > 0) {
        float* rb = &lds[((c * 3 + (g - 1)) * 64 + lane) * RSTRIDE];
        #pragma unroll
        for (int i = 0; i < 4; ++i)
            *(float4*)&rb[i * 4] = make_float4(acc[i*4], acc[i*4+1],
                                               acc[i*4+2], acc[i*4+3]);
    }
    __syncthreads();

    if (g == 0) {                        // one wave per c runs the epilogue
        #pragma unroll
        for (int r = 0; r < 3; ++r) {
            const float* rb = &lds[((c * 3 + r) * 64 + lane) * RSTRIDE];
            #pragma unroll
            for (int i = 0; i < 4; ++i) {
                const float4 v = *(const float4*)&rb[i * 4];
                acc[i*4]   += v.x;  acc[i*4+1] += v.y;
                acc[i*4+2] += v.z;  acc[i*4+3] += v.w;
            }
        }

        // ---- overlap-add: t = k*8+j = frames[k][j] + frames[k-1][8+j] ----
        float* ob = out + (size_t)(m * C_ + c) * T_ + (size_t)kk * HOP;
        float cmb[8];
        #pragma unroll
        for (int j = 0; j < 8; ++j) {
            const float pv = __shfl_up(acc[8 + j], 1);   // frames[kk-1][8+j]
            cmb[j] = acc[j] + pv;
        }
        if (lane == 0) {
            float* hb = ws + (size_t)((m * C_ + c) * NB + bb) * 8;
            *(float4*)&hb[0] = make_float4(acc[0], acc[1], acc[2], acc[3]);
            *(float4*)&hb[4] = make_float4(acc[4], acc[5], acc[6], acc[7]);
        } else {
            *(float4*)&ob[0] = make_float4(cmb[0], cmb[1], cmb[2], cmb[3]);
            *(float4*)&ob[4] = make_float4(cmb[4], cmb[5], cmb[6], cmb[7]);
        }
        if (lane == 63) {
            float* tb = ws + WS_TAIL_OFF + (size_t)((m * C_ + c) * NB + bb) * 8;
            *(float4*)&tb[0] = make_float4(acc[8],  acc[9],  acc[10], acc[11]);
            *(float4*)&tb[4] = make_float4(acc[12], acc[13], acc[14], acc[15]);
        }
    }
}

// out[bb*512 + j] = head[bb] + tail[bb-1]; global tail = tail[NB-1].
__global__ __launch_bounds__(256)
void boundary_kernel(const float* __restrict__ ws, float* __restrict__ out) {
    const int id = blockIdx.x * 256 + threadIdx.x;
    const int total = M_ * C_ * NB * 8;
    if (id >= total) return;
    const int j  = id & 7;
    const int bb = (id >> 3) % NB;
    const int mc = (id >> 3) / NB;
    float v = ws[(size_t)(mc * NB + bb) * 8 + j];
    if (bb > 0) v += ws[WS_TAIL_OFF + (size_t)(mc * NB + bb - 1) * 8 + j];
    out[(size_t)mc * T_ + (size_t)bb * (BK * HOP) + j] = v;
    if (bb == NB - 1) {
        out[(size_t)mc * T_ + (size_t)K_ * HOP + j] =
            ws[WS_TAIL_OFF + (size_t)(mc * NB + bb) * 8 + j];
    }
}

extern "C" void kernel_launch(void* const* d_in, const int* in_sizes, int n_in,
                              void* d_out, int out_size, void* d_ws, size_t ws_size,
                              hipStream_t stream) {
    const float* mix  = (const float*)d_in[0];
    const float* mask = (const float*)d_in[1];
    const float* Wg   = (const float*)d_in[2];
    float* out = (float*)d_out;
    float* ws  = (float*)d_ws;

    decoder_kernel<<<dim3(GRID), dim3(512), 0, stream>>>(mix, mask, Wg, out, ws);
    boundary_kernel<<<dim3((M_ * C_ * NB * 8 + 255) / 256), dim3(256), 0, stream>>>(ws, out);
}